// Round 2
// baseline (362.749 us; speedup 1.0000x reference)
//
#include <hip/hip_runtime.h>

#define BINS 10
#define COPIES 64      // one histogram copy per lane-id; waves share via LDS atomics
#define HSTRIDE 11     // 10 bins + 1 pad (odd stride -> 2-way bank aliasing max, free)

// One streaming pass: per-bin BCE sums + counts into LDS histograms, then
// per-block reduce -> global atomics.  loss = sum_b S_b / (c_b * n_nonempty).
// Key algebra: q = t ? p : (1-p) = 1 - |p-t| = 1-g, so bce = -log(1-g): no select.
__global__ __launch_bounds__(256) void ghm_partial(
    const float4* __restrict__ p4,
    const float4* __restrict__ t4,
    float* __restrict__ gsum,          // [BINS] in d_ws
    unsigned int* __restrict__ gcnt,   // [BINS] in d_ws
    int n4)
{
    __shared__ float        s_sum[COPIES * HSTRIDE];
    __shared__ unsigned int s_cnt[COPIES * HSTRIDE];

    const int tid = threadIdx.x;
    for (int k = tid; k < COPIES * HSTRIDE; k += 256) {
        s_sum[k] = 0.0f;
        s_cnt[k] = 0u;
    }
    __syncthreads();

    const int lane_base = (tid & 63) * HSTRIDE;
    const int start  = blockIdx.x * blockDim.x + tid;
    const int stride = gridDim.x * blockDim.x;
    const int iters  = n4 / stride;     // 16 for 2048x256 at n4 = 2^23

    int i = start;
#pragma unroll 4
    for (int it = 0; it < iters; ++it, i += stride) {
        float4 p = p4[i];
        float4 t = t4[i];
        float pe[4] = {p.x, p.y, p.z, p.w};
        float te[4] = {t.x, t.y, t.z, t.w};
#pragma unroll
        for (int e = 0; e < 4; ++e) {
            float g   = fabsf(pe[e] - te[e]);   // same expr as reference
            float bce = -__logf(1.0f - g);      // = -log(q), q = t?p:1-p
            int   bi  = (int)(g * 10.0f);       // trunc == floor (g >= 0)
            bi = bi > (BINS - 1) ? (BINS - 1) : bi;
            int idx = lane_base + bi;
            __hip_atomic_fetch_add(&s_sum[idx], bce, __ATOMIC_RELAXED,
                                   __HIP_MEMORY_SCOPE_WORKGROUP);
            __hip_atomic_fetch_add(&s_cnt[idx], 1u, __ATOMIC_RELAXED,
                                   __HIP_MEMORY_SCOPE_WORKGROUP);
        }
    }
    // tail (n4 not divisible by grid size)
    for (int j = iters * stride + start; j < n4; j += stride) {
        float4 p = p4[j];
        float4 t = t4[j];
        float pe[4] = {p.x, p.y, p.z, p.w};
        float te[4] = {t.x, t.y, t.z, t.w};
#pragma unroll
        for (int e = 0; e < 4; ++e) {
            float g   = fabsf(pe[e] - te[e]);
            float bce = -__logf(1.0f - g);
            int   bi  = (int)(g * 10.0f);
            bi = bi > (BINS - 1) ? (BINS - 1) : bi;
            int idx = lane_base + bi;
            __hip_atomic_fetch_add(&s_sum[idx], bce, __ATOMIC_RELAXED,
                                   __HIP_MEMORY_SCOPE_WORKGROUP);
            __hip_atomic_fetch_add(&s_cnt[idx], 1u, __ATOMIC_RELAXED,
                                   __HIP_MEMORY_SCOPE_WORKGROUP);
        }
    }

    __syncthreads();
    // reduce the 64 copies; lanes 0-9 handle sums, lanes 16-25 handle counts
    if (tid < BINS) {
        float s = 0.0f;
        for (int l = 0; l < COPIES; ++l) s += s_sum[l * HSTRIDE + tid];
        atomicAdd(&gsum[tid], s);
    }
    if (tid >= 16 && tid < 16 + BINS) {
        const int b = tid - 16;
        unsigned int c = 0u;
        for (int l = 0; l < COPIES; ++l) c += s_cnt[l * HSTRIDE + b];
        atomicAdd(&gcnt[b], c);
    }
}

__global__ void ghm_finalize(const float* __restrict__ gsum,
                             const unsigned int* __restrict__ gcnt,
                             float* __restrict__ out)
{
    if (threadIdx.x == 0 && blockIdx.x == 0) {
        int n = 0;
#pragma unroll
        for (int b = 0; b < BINS; ++b) n += (gcnt[b] > 0) ? 1 : 0;
        float nn = (float)(n > 0 ? n : 1);
        float acc = 0.0f;
#pragma unroll
        for (int b = 0; b < BINS; ++b) {
            if (gcnt[b] > 0)
                acc += gsum[b] / ((float)gcnt[b] * nn);
        }
        out[0] = acc;
    }
}

extern "C" void kernel_launch(void* const* d_in, const int* in_sizes, int n_in,
                              void* d_out, int out_size, void* d_ws, size_t ws_size,
                              hipStream_t stream)
{
    const float* p = (const float*)d_in[0];   // inputs (probabilities)
    const float* t = (const float*)d_in[1];   // targets (0/1 floats)
    const int n  = in_sizes[0];               // 262144*128
    const int n4 = n >> 2;                    // divisible by 4

    float*        gsum = (float*)d_ws;
    unsigned int* gcnt = (unsigned int*)((char*)d_ws + BINS * sizeof(float));

    // d_ws is re-poisoned to 0xAA before every timed launch — zero it (capturable)
    hipMemsetAsync(d_ws, 0, BINS * (sizeof(float) + sizeof(unsigned int)), stream);

    const int threads = 256;
    const int blocks  = 2048;   // 8 blocks/CU; 16 float4 iters/thread at this size
    ghm_partial<<<blocks, threads, 0, stream>>>(
        (const float4*)p, (const float4*)t, gsum, gcnt, n4);

    ghm_finalize<<<1, 64, 0, stream>>>(gsum, gcnt, (float*)d_out);
}

// Round 3
// 314.413 us; speedup vs baseline: 1.1537x; 1.1537x over previous
//
#include <hip/hip_runtime.h>

#define BINS 10

// Per-float4-pair body: 4 elems, register histogram update.
// Algebra: q = t?p:(1-p) = 1-|p-t| = 1-g, so bce = -log(1-g) (no select).
__device__ __forceinline__ void proc4(const float4 p, const float4 t,
                                      float* __restrict__ sb,
                                      float* __restrict__ cb)
{
    float pe[4] = {p.x, p.y, p.z, p.w};
    float te[4] = {t.x, t.y, t.z, t.w};
#pragma unroll
    for (int e = 0; e < 4; ++e) {
        float g   = fabsf(pe[e] - te[e]);   // same expr as reference
        float bce = -__logf(1.0f - g);      // = -log(q)
        int   bi  = (int)(g * 10.0f);       // trunc == floor (g >= 0)
        bi = bi > (BINS - 1) ? (BINS - 1) : bi;
#pragma unroll
        for (int b = 0; b < BINS; ++b) {
            bool hit = (bi == b);           // one v_cmp, vcc shared by both cndmasks
            sb[b] += hit ? bce  : 0.0f;
            cb[b] += hit ? 1.0f : 0.0f;
        }
    }
}

__global__ __launch_bounds__(256, 4) void ghm_partial(
    const float4* __restrict__ p4,
    const float4* __restrict__ t4,
    float* __restrict__ gsum,          // [BINS] floats in d_ws
    float* __restrict__ gcnt,          // [BINS] floats in d_ws
    int n4)
{
    float sb[BINS];
    float cb[BINS];
#pragma unroll
    for (int b = 0; b < BINS; ++b) { sb[b] = 0.0f; cb[b] = 0.0f; }

    const int tid    = threadIdx.x;
    const int start  = blockIdx.x * blockDim.x + tid;
    const int stride = gridDim.x * blockDim.x;
    const int iters  = n4 / stride;     // 16 at 2048x256, n4 = 2^23

    // -------- explicit depth-2 software pipeline: >=4 loads in flight --------
    if (iters >= 2) {
        int i = start;
        float4 p0 = p4[i],          t0 = t4[i];
        float4 p1 = p4[i + stride], t1 = t4[i + stride];
        i += 2 * stride;
        for (int it = 0; it < iters - 2; ++it, i += stride) {
            float4 pn = p4[i], tn = t4[i];     // prefetch next before consuming
            proc4(p0, t0, sb, cb);
            p0 = p1; t0 = t1;
            p1 = pn; t1 = tn;
        }
        proc4(p0, t0, sb, cb);
        proc4(p1, t1, sb, cb);
    } else {
        for (int i = start; i < iters * stride; i += stride)
            proc4(p4[i], t4[i], sb, cb);
    }
    // tail (n4 not divisible by grid size)
    for (int j = iters * stride + start; j < n4; j += stride)
        proc4(p4[j], t4[j], sb, cb);

    // -------- epilogue: wave shuffle-reduce -> LDS -> global atomics --------
    __shared__ float red[2 * BINS];
    if (tid < 2 * BINS) red[tid] = 0.0f;
    __syncthreads();

    const int lane = tid & 63;
#pragma unroll
    for (int b = 0; b < BINS; ++b) {
        float s = sb[b], c = cb[b];
#pragma unroll
        for (int off = 32; off > 0; off >>= 1) {
            s += __shfl_down(s, off);
            c += __shfl_down(c, off);
        }
        if (lane == 0) {
            atomicAdd(&red[b], s);
            atomicAdd(&red[BINS + b], c);
        }
    }
    __syncthreads();
    if (tid < BINS)                    atomicAdd(&gsum[tid], red[tid]);
    if (tid >= BINS && tid < 2 * BINS) atomicAdd(&gcnt[tid - BINS], red[tid]);
}

__global__ void ghm_finalize(const float* __restrict__ gsum,
                             const float* __restrict__ gcnt,
                             float* __restrict__ out)
{
    if (threadIdx.x == 0 && blockIdx.x == 0) {
        int n = 0;
#pragma unroll
        for (int b = 0; b < BINS; ++b) n += (gcnt[b] > 0.0f) ? 1 : 0;
        float nn = (float)(n > 0 ? n : 1);
        float acc = 0.0f;
#pragma unroll
        for (int b = 0; b < BINS; ++b) {
            if (gcnt[b] > 0.0f)
                acc += gsum[b] / (gcnt[b] * nn);   // counts < 2^24: exact in f32
        }
        out[0] = acc;
    }
}

extern "C" void kernel_launch(void* const* d_in, const int* in_sizes, int n_in,
                              void* d_out, int out_size, void* d_ws, size_t ws_size,
                              hipStream_t stream)
{
    const float* p = (const float*)d_in[0];   // inputs (probabilities)
    const float* t = (const float*)d_in[1];   // targets (0/1 floats)
    const int n  = in_sizes[0];               // 262144*128
    const int n4 = n >> 2;                    // divisible by 4

    float* gsum = (float*)d_ws;
    float* gcnt = gsum + BINS;

    // d_ws is re-poisoned to 0xAA before every timed launch — zero it (capturable)
    hipMemsetAsync(d_ws, 0, 2 * BINS * sizeof(float), stream);

    const int threads = 256;
    const int blocks  = 2048;   // iters = 16 at this size; grid-stride handles rest
    ghm_partial<<<blocks, threads, 0, stream>>>(
        (const float4*)p, (const float4*)t, gsum, gcnt, n4);

    ghm_finalize<<<1, 64, 0, stream>>>(gsum, gcnt, (float*)d_out);
}

// Round 4
// 293.030 us; speedup vs baseline: 1.2379x; 1.0730x over previous
//
#include <hip/hip_runtime.h>

#define BINS 10

// Per-element update.
// Algebra: q = t?p:(1-p) = 1-|p-t| = 1-g, so bce = -log(1-g) = -ln2*log2(1-g).
// We accumulate log2(1-g) (negative) and fold -ln2 into the finalize kernel.
// Counts: ballot -> popc on the SCALAR pipe (v_cmp result shared with cndmask).
__device__ __forceinline__ void elem(float p, float t,
                                     float* __restrict__ sb,
                                     unsigned int* __restrict__ cw)
{
    float g  = fabsf(p - t);          // same expr as reference
    float l2 = __log2f(1.0f - g);     // v_log_f32, no mul
    int   bi = (int)(g * 10.0f);      // g in (0.01,0.99): bi in [0,9], no clamp
#pragma unroll
    for (int b = 0; b < BINS; ++b) {
        bool hit = (bi == b);                      // one v_cmp -> sgpr pair
        unsigned long long m = __ballot(hit);      // reuses the compare
        sb[b] += hit ? l2 : 0.0f;                  // cndmask + add
        cw[b] += (unsigned int)__popcll(m);        // s_bcnt1 + s_add (scalar pipe)
    }
}

__device__ __forceinline__ void proc8(const float4 pa, const float4 pb,
                                      const float4 ta, const float4 tb,
                                      float* __restrict__ sb,
                                      unsigned int* __restrict__ cw)
{
    elem(pa.x, ta.x, sb, cw); elem(pa.y, ta.y, sb, cw);
    elem(pa.z, ta.z, sb, cw); elem(pa.w, ta.w, sb, cw);
    elem(pb.x, tb.x, sb, cw); elem(pb.y, tb.y, sb, cw);
    elem(pb.z, tb.z, sb, cw); elem(pb.w, tb.w, sb, cw);
}

__global__ __launch_bounds__(256, 4) void ghm_partial(
    const float4* __restrict__ p4,
    const float4* __restrict__ t4,
    float* __restrict__ gsum,          // [BINS] floats in d_ws
    unsigned int* __restrict__ gcnt,   // [BINS] uints in d_ws
    int n4)
{
    float        sb[BINS];
    unsigned int cw[BINS];
#pragma unroll
    for (int b = 0; b < BINS; ++b) { sb[b] = 0.0f; cw[b] = 0u; }

    const int tid     = threadIdx.x;
    const int start   = blockIdx.x * blockDim.x + tid;
    const int stride  = gridDim.x * blockDim.x;
    const int stride2 = 2 * stride;
    const int nouter  = n4 / stride2;   // 8 at 2048x256, n4 = 2^23

    // depth-2 pipeline, 2 float4-pairs per stage: 8 loads (128 B) in flight
    if (nouter >= 2) {
        int i = start;
        float4 pa0 = p4[i], pb0 = p4[i + stride];
        float4 ta0 = t4[i], tb0 = t4[i + stride];
        i += stride2;
        float4 pa1 = p4[i], pb1 = p4[i + stride];
        float4 ta1 = t4[i], tb1 = t4[i + stride];
        i += stride2;
        for (int it = 0; it < nouter - 2; ++it, i += stride2) {
            float4 na = p4[i], nb = p4[i + stride];   // prefetch next stage
            float4 ma = t4[i], mb = t4[i + stride];
            proc8(pa0, pb0, ta0, tb0, sb, cw);
            pa0 = pa1; pb0 = pb1; ta0 = ta1; tb0 = tb1;
            pa1 = na;  pb1 = nb;  ta1 = ma;  tb1 = mb;
        }
        proc8(pa0, pb0, ta0, tb0, sb, cw);
        proc8(pa1, pb1, ta1, tb1, sb, cw);
    } else {
        for (int k = 0; k < 2 * nouter; ++k) {
            int i = start + k * stride;
            float4 p = p4[i], t = t4[i];
            elem(p.x, t.x, sb, cw); elem(p.y, t.y, sb, cw);
            elem(p.z, t.z, sb, cw); elem(p.w, t.w, sb, cw);
        }
    }
    // tail (n4 not divisible by 2*stride)
    for (int j = start + nouter * stride2; j < n4; j += stride) {
        float4 p = p4[j], t = t4[j];
        elem(p.x, t.x, sb, cw); elem(p.y, t.y, sb, cw);
        elem(p.z, t.z, sb, cw); elem(p.w, t.w, sb, cw);
    }

    // -------- epilogue: wave reduce -> LDS -> one global atomic/bin/block ----
    __shared__ float        redS[BINS];
    __shared__ unsigned int redC[BINS];
    if (tid < BINS) { redS[tid] = 0.0f; redC[tid] = 0u; }
    __syncthreads();

    const int lane = tid & 63;
#pragma unroll
    for (int b = 0; b < BINS; ++b) {
        float s = sb[b];
#pragma unroll
        for (int off = 32; off > 0; off >>= 1) s += __shfl_down(s, off);
        if (lane == 0) {
            atomicAdd(&redS[b], s);
            atomicAdd(&redC[b], cw[b]);   // cw is wave-uniform (ballot-derived)
        }
    }
    __syncthreads();
    if (tid < BINS) {
        atomicAdd(&gsum[tid], redS[tid]);
        atomicAdd(&gcnt[tid], redC[tid]);
    }
}

__global__ void ghm_finalize(const float* __restrict__ gsum,
                             const unsigned int* __restrict__ gcnt,
                             float* __restrict__ out)
{
    if (threadIdx.x == 0 && blockIdx.x == 0) {
        int n = 0;
#pragma unroll
        for (int b = 0; b < BINS; ++b) n += (gcnt[b] > 0u) ? 1 : 0;
        float nn = (float)(n > 0 ? n : 1);
        float acc = 0.0f;
#pragma unroll
        for (int b = 0; b < BINS; ++b) {
            if (gcnt[b] > 0u)
                acc += gsum[b] / ((float)gcnt[b] * nn);  // counts < 2^24: exact
        }
        out[0] = -0.6931471805599453f * acc;   // fold -ln(2) from log2 domain
    }
}

extern "C" void kernel_launch(void* const* d_in, const int* in_sizes, int n_in,
                              void* d_out, int out_size, void* d_ws, size_t ws_size,
                              hipStream_t stream)
{
    const float* p = (const float*)d_in[0];   // inputs (probabilities)
    const float* t = (const float*)d_in[1];   // targets (0/1 floats)
    const int n  = in_sizes[0];               // 262144*128
    const int n4 = n >> 2;                    // divisible by 4

    float*        gsum = (float*)d_ws;
    unsigned int* gcnt = (unsigned int*)((char*)d_ws + BINS * sizeof(float));

    // d_ws is re-poisoned to 0xAA before every timed launch — zero it (capturable)
    hipMemsetAsync(d_ws, 0, BINS * (sizeof(float) + sizeof(unsigned int)), stream);

    const int threads = 256;
    const int blocks  = 2048;   // nouter = 8 at this size; tail handles the rest
    ghm_partial<<<blocks, threads, 0, stream>>>(
        (const float4*)p, (const float4*)t, gsum, gcnt, n4);

    ghm_finalize<<<1, 64, 0, stream>>>(gsum, gcnt, (float*)d_out);
}